// Round 8
// baseline (157.282 us; speedup 1.0000x reference)
//
#include <hip/hip_runtime.h>
#include <hip/hip_bf16.h>
#include <cstdint>
#include <cstddef>

#define BATCH 4096
#define INC   1024
#define OUTC  1024
#define NB    8
#define KDIM  (INC * NB)   // 8192 (elements == bytes in i8)

// GEMM: 256x256 tile, BK=64 B i8, 8 waves (2M x 4N), wave tile 128x64 (8x4 frags
// of 16x16x64 i8). FAITHFUL m201 8-phase port: per K-step, 4 phases of
// {3 ds_read(step s+1) | 1 global_load_lds(step s+3) -> barrier -> counted
// lgkmcnt -> setprio + 8 MFMA (one quadrant of step s) -> barrier}. vmcnt(4)
// once per step (never a drain); ph3's lgkmcnt(0) gives the block-wide
// "all reads done" invariant that makes staging into slot s%3 WAR-safe.
// 3 LDS slots (96 KiB static), XOR-swizzle (T2, verified), XCD swizzle (T1),
// packed-coalesced partial epilogue (R7).
#define BM 256
#define BN 256
#define BKB 64                  // k-bytes per step
#define SPLITS 4
#define KZ (KDIM / SPLITS)      // 2048 bytes per z
#define KSTEPS (KZ / BKB)       // 32 even steps
#define GRID_BLOCKS ((OUTC / BN) * (BATCH / BM) * SPLITS)   // 4*16*4 = 256 = 1 block/CU
#define FRAG (16 * BKB)         // 1024 B between fragment rows

// prep dispatch partition: expand | fused rowmax+quant (one block per coeff row)
#define EXPAND_BLOCKS  ((BATCH * INC) / 256)   // 16384
#define QUANT_BLOCKS   OUTC                    // 1024
#define PREP_BLOCKS    (EXPAND_BLOCKS + QUANT_BLOCKS)

typedef int      v4i __attribute__((ext_vector_type(4)));
typedef unsigned v4u __attribute__((ext_vector_type(4)));
typedef char     v8c __attribute__((ext_vector_type(8)));

__device__ __forceinline__ unsigned short f2bf(float f) {
  union { float f; unsigned u; } v; v.f = f;
  unsigned r = v.u + 0x7fffu + ((v.u >> 16) & 1u);  // round-to-nearest-even
  return (unsigned short)(r >> 16);
}
__device__ __forceinline__ float bf2f(unsigned short h) {
  union { unsigned u; float f; } v; v.u = ((unsigned)h) << 16; return v.f;
}

// async 16B global -> LDS (DMA; LDS dest = wave-uniform base + lane*16)
__device__ __forceinline__ void gld16(const char* g, char* l) {
  __builtin_amdgcn_global_load_lds(
      (const __attribute__((address_space(1))) unsigned int*)g,
      (__attribute__((address_space(3))) unsigned int*)l, 16, 0, 0);
}

// ---------------- Phase 1 (fused dispatch): expand basis | rowmax+quantize coeffs -------
__global__ __launch_bounds__(256) void prep_kernel(
    const float* __restrict__ x, const float4* __restrict__ coeffs4,
    const float* __restrict__ centers, const float* __restrict__ slopes,
    const float* __restrict__ alpha, const float* __restrict__ beta,
    char* __restrict__ Ai8, int* __restrict__ Ci8i,
    float* __restrict__ maxrow, int* __restrict__ qcsum) {
  const int blk = blockIdx.x;
  const int tid = threadIdx.x;
  if (blk < EXPAND_BLOCKS) {
    const int idx = blk * 256 + tid;          // (b,i) pair
    const int i = idx & (INC - 1);
    const float u = alpha[i] * x[idx] + beta[i];
    const float s0 = slopes[i * NB];
    const float c0 = centers[i * NB];
    const float c1 = centers[i * NB + 1];
    const float L2E2 = 2.8853900817779268f;   // 2*log2(e)
    const float a2 = L2E2 * s0;
    float e = __builtin_amdgcn_exp2f(a2 * (c0 - u));   // inf -> rcp -> 0: correct limit
    const float R = __builtin_amdgcn_exp2f(a2 * (c1 - c0));
    v8c q;
#pragma unroll
    for (int m = 0; m < 8; ++m) {
      float basis = __builtin_amdgcn_rcpf(1.0f + e);
      q[m] = (char)(int)rintf(basis * 254.0f - 127.0f);
      e *= R;
    }
    *(v8c*)(Ai8 + (size_t)idx * 8) = q;   // 8B coalesced store
  } else {
    const int o = blk - EXPAND_BLOCKS;
    const float4* row = coeffs4 + (size_t)o * (KDIM / 4);
    float4 v[8];
    float m = 0.0f;
#pragma unroll
    for (int j = 0; j < 8; ++j) {
      v[j] = row[tid + 256 * j];
      m = fmaxf(m, fmaxf(fmaxf(fabsf(v[j].x), fabsf(v[j].y)),
                         fmaxf(fabsf(v[j].z), fabsf(v[j].w))));
    }
#pragma unroll
    for (int off = 32; off; off >>= 1) m = fmaxf(m, __shfl_xor(m, off));
    __shared__ float wm[4];
    __shared__ int   wq[4];
    if ((tid & 63) == 0) wm[tid >> 6] = m;
    __syncthreads();
    const float M = fmaxf(fmaxf(fmaxf(wm[0], wm[1]), fmaxf(wm[2], wm[3])), 1e-30f);
    const float s = 127.0f / M;
    int qs = 0;
#pragma unroll
    for (int j = 0; j < 8; ++j) {
      int q0 = (int)rintf(v[j].x * s), q1 = (int)rintf(v[j].y * s);
      int q2 = (int)rintf(v[j].z * s), q3 = (int)rintf(v[j].w * s);
      Ci8i[(size_t)o * (KDIM / 4) + tid + 256 * j] =
          (q0 & 0xFF) | ((q1 & 0xFF) << 8) | ((q2 & 0xFF) << 16) | ((q3 & 0xFF) << 24);
      qs += q0 + q1 + q2 + q3;
    }
#pragma unroll
    for (int off = 32; off; off >>= 1) qs += __shfl_xor(qs, off);
    if ((tid & 63) == 0) wq[tid >> 6] = qs;
    __syncthreads();
    if (tid == 0) { maxrow[o] = M; qcsum[o] = wq[0] + wq[1] + wq[2] + wq[3]; }
  }
}

// ---------------- Phase 2: i8 16x16x64 MFMA GEMM, 8-phase fine pipeline ------------
// Swizzle (T2, verified R2-R7): LDS slot (row, gs) holds global 16B k-group
// gg = gs ^ ((row>>1)&3); staging LDS dest LINEAR in lane; inverse swizzle on
// per-lane global source, forward swizzle on ds_read offset (kx).
// Half h = step s: MFMA step s (regs, set X), read step s+1 (slot (s+1)%3, set Y),
// stage step s+3 (slot s%3). vmcnt(4)@ph0 = s+1 landed (s+2 in flight).
// lgkm gates 3/6/9/0: ph0's 3 forces set X complete; ph3's 0 forces ALL ds_reads
// complete -> closing barrier publishes WAR-safety for next half's staging.
__global__ __launch_bounds__(512, 2) void gemm_kernel(
    const char* __restrict__ A, const char* __restrict__ C,
    unsigned* __restrict__ partials) {
  __shared__ __align__(16) char As[3][BM * BKB];   // 3 x 16 KiB
  __shared__ __align__(16) char Bs[3][BN * BKB];   // 3 x 16 KiB

  // XCD-aware bijective remap: each XCD owns 32 consecutive logical blocks
  const int id = (blockIdx.x & 7) * (GRID_BLOCKS / 8) + (blockIdx.x >> 3);
  const int z  = id >> 6;          // 64 blocks per z-plane
  const int p  = id & 63;
  const int by = p >> 2;           // 16 M-tiles
  const int bx = p & 3;            // 4 N-tiles
  const int bm0 = by * BM;
  const int bn0 = bx * BN;
  const int kt0 = z * KZ;

  const int tid  = threadIdx.x;
  const int wave = tid >> 6;
  const int lane = tid & 63;
  const int quad = lane >> 4;
  const int lm   = lane & 15;
  const int wm   = (wave >> 2) * 128;   // 2 M-wave-groups
  const int wn   = (wave & 3) * 64;     // 4 N-wave-groups

  // staging decode: lane -> slot (row = rb+(lane>>2), gs = lane&3);
  // global group gg = gs ^ ((row>>1)&3)
  const int r4 = lane >> 2;
  const int gg = (lane & 3) ^ ((lane >> 3) & 3);

  const char* pA0 = A + (size_t)(bm0 + wave * 32 + r4) * KDIM + kt0 + gg * 16;
  const char* pB0 = C + (size_t)(bn0 + wave * 32 + r4) * KDIM + kt0 + gg * 16;
  const int lo = wave * 32 * BKB;   // wave's LDS base within a slot

  const int kx   = (quad ^ ((lm >> 1) & 3)) * 16;   // swizzled ds_read group offset
  const int aoff = (wm + lm) * BKB + kx;            // + f*FRAG per fragment
  const int boff = (wn + lm) * BKB + kx;

  v4i acc[8][4] = {};
  v4i xa[8], xb[4], ya[8], yb[4];   // two named operand sets
  int srd = 0;   // slot of next step to ds_read
  int sst = 0;   // slot of next step to stage

#define STAGE_FULL()                                                         \
  {                                                                          \
    gld16(pA0,                     As[sst] + lo);                            \
    gld16(pA0 + (size_t)16 * KDIM, As[sst] + lo + 16 * BKB);                 \
    gld16(pB0,                     Bs[sst] + lo);                            \
    gld16(pB0 + (size_t)16 * KDIM, Bs[sst] + lo + 16 * BKB);                 \
    pA0 += BKB; pB0 += BKB;                                                  \
    sst = (sst == 2) ? 0 : sst + 1;                                          \
  }

#define MFMA8(AS, BS, FM0, FN0)                                              \
  {                                                                          \
    __builtin_amdgcn_s_setprio(1);                                           \
    _Pragma("unroll")                                                        \
    for (int fm = 0; fm < 4; ++fm)                                           \
      _Pragma("unroll")                                                      \
      for (int fn = 0; fn < 2; ++fn)                                         \
        acc[FM0 + fm][FN0 + fn] = __builtin_amdgcn_mfma_i32_16x16x64_i8(     \
            AS[FM0 + fm], BS[FN0 + fn], acc[FM0 + fm][FN0 + fn], 0, 0, 0);   \
    __builtin_amdgcn_s_setprio(0);                                           \
  }

#define GATE(S)                                                              \
  asm volatile("s_waitcnt lgkmcnt(" S ")" ::: "memory");                     \
  __builtin_amdgcn_sched_barrier(0);

  // HALF with reads + staging (h = 0..28)
#define HALF_MAIN(AX, BX, AY, BY)                                            \
  {                                                                          \
    const char* cA = As[srd] + aoff;                                         \
    const char* cB = Bs[srd] + boff;                                         \
    /* ph0 */                                                                \
    AY[0] = *(const v4i*)(cA + 0 * FRAG);                                    \
    AY[1] = *(const v4i*)(cA + 1 * FRAG);                                    \
    AY[2] = *(const v4i*)(cA + 2 * FRAG);                                    \
    gld16(pA0, As[sst] + lo);                                                \
    asm volatile("s_waitcnt vmcnt(4)" ::: "memory");                         \
    __builtin_amdgcn_sched_barrier(0);                                       \
    __builtin_amdgcn_s_barrier();                                            \
    GATE("3")                                                                \
    MFMA8(AX, BX, 0, 0)                                                      \
    __builtin_amdgcn_s_barrier();                                            \
    /* ph1 */                                                                \
    AY[3] = *(const v4i*)(cA + 3 * FRAG);                                    \
    BY[0] = *(const v4i*)(cB + 0 * FRAG);                                    \
    BY[1] = *(const v4i*)(cB + 1 * FRAG);                                    \
    gld16(pA0 + (size_t)16 * KDIM, As[sst] + lo + 16 * BKB);                 \
    __builtin_amdgcn_s_barrier();                                            \
    GATE("6")                                                                \
    MFMA8(AX, BX, 0, 2)                                                      \
    __builtin_amdgcn_s_barrier();                                            \
    /* ph2 */                                                                \
    BY[2] = *(const v4i*)(cB + 2 * FRAG);                                    \
    BY[3] = *(const v4i*)(cB + 3 * FRAG);                                    \
    AY[4] = *(const v4i*)(cA + 4 * FRAG);                                    \
    gld16(pB0, Bs[sst] + lo);                                                \
    __builtin_amdgcn_s_barrier();                                            \
    GATE("9")                                                                \
    MFMA8(AX, BX, 4, 2)                                                      \
    __builtin_amdgcn_s_barrier();                                            \
    /* ph3 */                                                                \
    AY[5] = *(const v4i*)(cA + 5 * FRAG);                                    \
    AY[6] = *(const v4i*)(cA + 6 * FRAG);                                    \
    AY[7] = *(const v4i*)(cA + 7 * FRAG);                                    \
    gld16(pB0 + (size_t)16 * KDIM, Bs[sst] + lo + 16 * BKB);                 \
    __builtin_amdgcn_s_barrier();                                            \
    GATE("0")                                                                \
    MFMA8(AX, BX, 4, 0)                                                      \
    __builtin_amdgcn_s_barrier();                                            \
    pA0 += BKB; pB0 += BKB;                                                  \
    sst = (sst == 2) ? 0 : sst + 1;                                          \
    srd = (srd == 2) ? 0 : srd + 1;                                          \
  }

  // HALF with reads, no staging (h = 29, 30); VMS = vmcnt string
#define HALF_NOST(AX, BX, AY, BY, VMS)                                       \
  {                                                                          \
    const char* cA = As[srd] + aoff;                                         \
    const char* cB = Bs[srd] + boff;                                         \
    AY[0] = *(const v4i*)(cA + 0 * FRAG);                                    \
    AY[1] = *(const v4i*)(cA + 1 * FRAG);                                    \
    AY[2] = *(const v4i*)(cA + 2 * FRAG);                                    \
    asm volatile("s_waitcnt vmcnt(" VMS ")" ::: "memory");                   \
    __builtin_amdgcn_sched_barrier(0);                                       \
    __builtin_amdgcn_s_barrier();                                            \
    GATE("3")                                                                \
    MFMA8(AX, BX, 0, 0)                                                      \
    __builtin_amdgcn_s_barrier();                                            \
    AY[3] = *(const v4i*)(cA + 3 * FRAG);                                    \
    BY[0] = *(const v4i*)(cB + 0 * FRAG);                                    \
    BY[1] = *(const v4i*)(cB + 1 * FRAG);                                    \
    __builtin_amdgcn_s_barrier();                                            \
    GATE("6")                                                                \
    MFMA8(AX, BX, 0, 2)                                                      \
    __builtin_amdgcn_s_barrier();                                            \
    BY[2] = *(const v4i*)(cB + 2 * FRAG);                                    \
    BY[3] = *(const v4i*)(cB + 3 * FRAG);                                    \
    AY[4] = *(const v4i*)(cA + 4 * FRAG);                                    \
    __builtin_amdgcn_s_barrier();                                            \
    GATE("9")                                                                \
    MFMA8(AX, BX, 4, 2)                                                      \
    __builtin_amdgcn_s_barrier();                                            \
    AY[5] = *(const v4i*)(cA + 5 * FRAG);                                    \
    AY[6] = *(const v4i*)(cA + 6 * FRAG);                                    \
    AY[7] = *(const v4i*)(cA + 7 * FRAG);                                    \
    __builtin_amdgcn_s_barrier();                                            \
    GATE("0")                                                                \
    MFMA8(AX, BX, 4, 0)                                                      \
    __builtin_amdgcn_s_barrier();                                            \
    srd = (srd == 2) ? 0 : srd + 1;                                          \
  }

  // final half (h = 31): no reads, no staging
#define HALF_FIN(AX, BX)                                                     \
  {                                                                          \
    GATE("0")                                                                \
    MFMA8(AX, BX, 0, 0)                                                      \
    MFMA8(AX, BX, 0, 2)                                                      \
    MFMA8(AX, BX, 4, 2)                                                      \
    MFMA8(AX, BX, 4, 0)                                                      \
  }

  // prologue: stage steps 0,1,2 -> slots 0,1,2; read step 0 into set X
  STAGE_FULL(); STAGE_FULL(); STAGE_FULL();
  asm volatile("s_waitcnt vmcnt(8)" ::: "memory");   // step 0 landed
  __builtin_amdgcn_sched_barrier(0);
  __builtin_amdgcn_s_barrier();
  {
    const char* cA = As[0] + aoff;
    const char* cB = Bs[0] + boff;
#pragma unroll
    for (int f = 0; f < 8; ++f) xa[f] = *(const v4i*)(cA + f * FRAG);
#pragma unroll
    for (int f = 0; f < 4; ++f) xb[f] = *(const v4i*)(cB + f * FRAG);
  }
  srd = 1;   // next read: step 1 (slot 1); sst already 0 (step 3 -> slot 0)

  // h = 0..27 (14 pairs), then 28 / 29 / 30 / 31
  for (int i = 0; i < 14; ++i) {
    HALF_MAIN(xa, xb, ya, yb);   // even h: MFMA set X, read set Y
    HALF_MAIN(ya, yb, xa, xb);   // odd  h
  }
  HALF_MAIN(xa, xb, ya, yb);          // h=28 (stages step 31)
  HALF_NOST(ya, yb, xa, xb, "4");     // h=29
  HALF_NOST(xa, xb, ya, yb, "0");     // h=30
  HALF_FIN(ya, yb);                   // h=31
#undef HALF_FIN
#undef HALF_NOST
#undef HALF_MAIN
#undef GATE
#undef MFMA8
#undef STAGE_FULL

  // ---- packed epilogue: 64 bf16-pair words per lane, 16 coalesced dwordx4 stores ----
  unsigned w32[64];
#pragma unroll
  for (int fm = 0; fm < 8; ++fm)
#pragma unroll
    for (int fn = 0; fn < 4; ++fn)
#pragma unroll
      for (int rr = 0; rr < 2; ++rr)
        w32[fm * 8 + fn * 2 + rr] =
            (unsigned)f2bf((float)acc[fm][fn][2 * rr]) |
            ((unsigned)f2bf((float)acc[fm][fn][2 * rr + 1]) << 16);

  unsigned* outp = partials + (((size_t)z * 64 + p) * 8 + wave) * 4096 + lane * 4;
#pragma unroll
  for (int c = 0; c < 16; ++c)
    *(v4u*)(outp + c * 256) = v4u{w32[4 * c], w32[4 * c + 1], w32[4 * c + 2], w32[4 * c + 3]};
}

// ---------------- Phase 3: reduce + dequant + un-pack transpose ----------------
// One block per (p, w) 128x64 output region; sums 4 z-copies of the packed
// region (fully coalesced dwordx4), decodes (chunk,lane,word)->(b,o), dequants,
// transposes through LDS, writes out [b][o] coalesced.
__global__ __launch_bounds__(256) void reduce_kernel(
    const unsigned* __restrict__ P, const float* __restrict__ maxrow,
    const int* __restrict__ qcsum, float* __restrict__ out) {
  const int blk = blockIdx.x;         // 0..511
  const int p = blk >> 3, w = blk & 7;
  const int by = p >> 2, bx = p & 3;
  const int B0 = by * BM + (w >> 2) * 128;
  const int O0 = bx * BN + (w & 3) * 64;
  const int t = threadIdx.x;
  const int l = t & 63;

  __shared__ float tile[128][65];
  __shared__ float sM[64];
  __shared__ float sQ[64];
  if (t < 64) { sM[t] = maxrow[O0 + t]; sQ[t] = 127.0f * (float)qcsum[O0 + t]; }
  __syncthreads();

  const size_t region = ((size_t)p * 8 + w) * 4096;
  const size_t zs     = (size_t)64 * 8 * 4096;   // u32 per z-plane
  float slo[16] = {}, shi[16] = {};
#pragma unroll
  for (int z = 0; z < SPLITS; ++z) {
#pragma unroll
    for (int r = 0; r < 4; ++r) {
      v4u u = *(const v4u*)(P + z * zs + region + ((t >> 6) + r * 4) * 256 + l * 4);
#pragma unroll
      for (int i = 0; i < 4; ++i) {
        slo[r * 4 + i] += bf2f((unsigned short)(u[i] & 0xFFFFu));
        shi[r * 4 + i] += bf2f((unsigned short)(u[i] >> 16));
      }
    }
  }
  const float inv = 1.0f / 32258.0f;   // 127*254
#pragma unroll
  for (int r = 0; r < 4; ++r)
#pragma unroll
    for (int i = 0; i < 4; ++i) {
      const int jj = (t >> 6) * 4 + r * 16 + i;       // fm*8 + fn*2 + rr
      const int fm = jj >> 3, fn = (jj >> 1) & 3, rr = jj & 1;
      const int bl = fm * 16 + (l >> 4) * 4 + rr * 2;
      const int ol = fn * 16 + (l & 15);
      const float M = sM[ol], corr = sQ[ol];
      tile[bl][ol]     = M * (slo[r * 4 + i] + corr) * inv;
      tile[bl + 1][ol] = M * (shi[r * 4 + i] + corr) * inv;
    }
  __syncthreads();

  const int row = t >> 1;
  const int c0  = (t & 1) * 32;
  float* op = out + (size_t)(B0 + row) * OUTC + O0 + c0;
#pragma unroll
  for (int i = 0; i < 8; ++i)
    *(float4*)(op + 4 * i) = float4{tile[row][c0 + 4 * i],     tile[row][c0 + 4 * i + 1],
                                    tile[row][c0 + 4 * i + 2], tile[row][c0 + 4 * i + 3]};
}

extern "C" void kernel_launch(void* const* d_in, const int* in_sizes, int n_in,
                              void* d_out, int out_size, void* d_ws, size_t ws_size,
                              hipStream_t stream) {
  const float* x       = (const float*)d_in[0];
  const float* coeffs  = (const float*)d_in[1];
  const float* centers = (const float*)d_in[2];
  const float* slopes  = (const float*)d_in[3];
  const float* alpha   = (const float*)d_in[4];
  const float* beta    = (const float*)d_in[5];
  float* out = (float*)d_out;

  const size_t a_bytes    = (size_t)BATCH * KDIM;                 // 32 MiB i8
  const size_t c_bytes    = (size_t)OUTC * KDIM;                  // 8 MiB i8
  const size_t stat_bytes = OUTC * sizeof(float);                 // 4 KiB
  const size_t qcs_bytes  = OUTC * sizeof(int);                   // 4 KiB
  const size_t part_bytes = (size_t)SPLITS * BATCH * OUTC * 2;    // 32 MiB bf16-pairs
  if (ws_size < a_bytes + c_bytes + stat_bytes + qcs_bytes + part_bytes) return;

  char*  Ai8    = (char*)d_ws;
  char*  Ci8    = Ai8 + a_bytes;
  float* maxrow = (float*)(Ci8 + c_bytes);
  int*   qcsum  = (int*)((char*)maxrow + stat_bytes);
  unsigned* parts = (unsigned*)((char*)qcsum + qcs_bytes);

  prep_kernel<<<PREP_BLOCKS, 256, 0, stream>>>(
      x, (const float4*)coeffs, centers, slopes, alpha, beta,
      Ai8, (int*)Ci8, maxrow, qcsum);

  gemm_kernel<<<GRID_BLOCKS, 512, 0, stream>>>(Ai8, Ci8, parts);

  reduce_kernel<<<64 * 8, 256, 0, stream>>>(parts, maxrow, qcsum, out);
}

// Round 11
// 152.633 us; speedup vs baseline: 1.0305x; 1.0305x over previous
//
#include <hip/hip_runtime.h>
#include <hip/hip_bf16.h>
#include <cstdint>
#include <cstddef>

#define BATCH 4096
#define INC   1024
#define OUTC  1024
#define NB    8
#define KDIM  (INC * NB)   // 8192 (elements == bytes in i8)

// GEMM: 256x256 tile, BK=64 B i8, 8 waves (2M x 4N), wave tile 128x64 (8x4 frags
// of 16x16x64 i8). TRANSPORT experiment (reg-staging vs DMA), ASM-FREE version:
// R9/R10's hand-written vmcnt/s_barrier ledger failed twice at container level,
// so every wait here is COMPILER-GENERATED (it emits the counted vmcnt before
// the ds_write of last step's registers automatically) and the only sync is
// __syncthreads(). Loads for step t+2 issue at the TOP of step t, so the
// barrier's drain waits on loads with a full step (~1500 cyc) of MFMA cover
// vs ~900 cyc HBM latency -> residual drain ~0.
// Step t (cur = t&1): gload data t+2 -> set[t&1]; ds_read slot[cur];
// ds_write set[(t+1)&1] -> slot[cur^1]; 32 MFMA; __syncthreads.
// WAR ledger: slot[cur^1]'s readers were step t-1, drained by its barrier;
// slot[cur] was written at step t-1, published by its barrier.
// 2 LDS slots (64 KiB static), XOR-swizzle (T2, verified R2-R8), XCD swizzle
// (T1), setprio (T5), packed-coalesced partial epilogue (R7/R8, verified).
#define BM 256
#define BN 256
#define BKB 64                  // k-bytes per step
#define SPLITS 4
#define KZ (KDIM / SPLITS)      // 2048 bytes per z
#define KSTEPS (KZ / BKB)       // 32 even steps
#define GRID_BLOCKS ((OUTC / BN) * (BATCH / BM) * SPLITS)   // 4*16*4 = 256 = 1 block/CU
#define FRAG (16 * BKB)         // 1024 B between fragment rows

// prep dispatch partition: expand | fused rowmax+quant (one block per coeff row)
#define EXPAND_BLOCKS  ((BATCH * INC) / 256)   // 16384
#define QUANT_BLOCKS   OUTC                    // 1024
#define PREP_BLOCKS    (EXPAND_BLOCKS + QUANT_BLOCKS)

typedef int      v4i __attribute__((ext_vector_type(4)));
typedef unsigned v4u __attribute__((ext_vector_type(4)));
typedef char     v8c __attribute__((ext_vector_type(8)));

__device__ __forceinline__ unsigned short f2bf(float f) {
  union { float f; unsigned u; } v; v.f = f;
  unsigned r = v.u + 0x7fffu + ((v.u >> 16) & 1u);  // round-to-nearest-even
  return (unsigned short)(r >> 16);
}
__device__ __forceinline__ float bf2f(unsigned short h) {
  union { unsigned u; float f; } v; v.u = ((unsigned)h) << 16; return v.f;
}

// ---------------- Phase 1 (fused dispatch): expand basis | rowmax+quantize coeffs -------
__global__ __launch_bounds__(256) void prep_kernel(
    const float* __restrict__ x, const float4* __restrict__ coeffs4,
    const float* __restrict__ centers, const float* __restrict__ slopes,
    const float* __restrict__ alpha, const float* __restrict__ beta,
    char* __restrict__ Ai8, int* __restrict__ Ci8i,
    float* __restrict__ maxrow, int* __restrict__ qcsum) {
  const int blk = blockIdx.x;
  const int tid = threadIdx.x;
  if (blk < EXPAND_BLOCKS) {
    const int idx = blk * 256 + tid;          // (b,i) pair
    const int i = idx & (INC - 1);
    const float u = alpha[i] * x[idx] + beta[i];
    const float s0 = slopes[i * NB];
    const float c0 = centers[i * NB];
    const float c1 = centers[i * NB + 1];
    const float L2E2 = 2.8853900817779268f;   // 2*log2(e)
    const float a2 = L2E2 * s0;
    float e = __builtin_amdgcn_exp2f(a2 * (c0 - u));   // inf -> rcp -> 0: correct limit
    const float R = __builtin_amdgcn_exp2f(a2 * (c1 - c0));
    v8c q;
#pragma unroll
    for (int m = 0; m < 8; ++m) {
      float basis = __builtin_amdgcn_rcpf(1.0f + e);
      q[m] = (char)(int)rintf(basis * 254.0f - 127.0f);
      e *= R;
    }
    *(v8c*)(Ai8 + (size_t)idx * 8) = q;   // 8B coalesced store
  } else {
    const int o = blk - EXPAND_BLOCKS;
    const float4* row = coeffs4 + (size_t)o * (KDIM / 4);
    float4 v[8];
    float m = 0.0f;
#pragma unroll
    for (int j = 0; j < 8; ++j) {
      v[j] = row[tid + 256 * j];
      m = fmaxf(m, fmaxf(fmaxf(fabsf(v[j].x), fabsf(v[j].y)),
                         fmaxf(fabsf(v[j].z), fabsf(v[j].w))));
    }
#pragma unroll
    for (int off = 32; off; off >>= 1) m = fmaxf(m, __shfl_xor(m, off));
    __shared__ float wm[4];
    __shared__ int   wq[4];
    if ((tid & 63) == 0) wm[tid >> 6] = m;
    __syncthreads();
    const float M = fmaxf(fmaxf(fmaxf(wm[0], wm[1]), fmaxf(wm[2], wm[3])), 1e-30f);
    const float s = 127.0f / M;
    int qs = 0;
#pragma unroll
    for (int j = 0; j < 8; ++j) {
      int q0 = (int)rintf(v[j].x * s), q1 = (int)rintf(v[j].y * s);
      int q2 = (int)rintf(v[j].z * s), q3 = (int)rintf(v[j].w * s);
      Ci8i[(size_t)o * (KDIM / 4) + tid + 256 * j] =
          (q0 & 0xFF) | ((q1 & 0xFF) << 8) | ((q2 & 0xFF) << 16) | ((q3 & 0xFF) << 24);
      qs += q0 + q1 + q2 + q3;
    }
#pragma unroll
    for (int off = 32; off; off >>= 1) qs += __shfl_xor(qs, off);
    if ((tid & 63) == 0) wq[tid >> 6] = qs;
    __syncthreads();
    if (tid == 0) { maxrow[o] = M; qcsum[o] = wq[0] + wq[1] + wq[2] + wq[3]; }
  }
}

// ---------------- Phase 2: i8 16x16x64 MFMA GEMM, reg-staged (asm-free) ------------
// Swizzle (T2, verified R2-R8): LDS slot (row, gs) holds global 16B k-group
// gg = gs ^ ((row>>1)&3); inverse swizzle on per-lane GLOBAL address, LDS write
// LINEAR in lane (base + lane*16), forward swizzle on ds_read offset (kx).
__global__ __launch_bounds__(512, 2) void gemm_kernel(
    const char* __restrict__ A, const char* __restrict__ C,
    unsigned* __restrict__ partials) {
  __shared__ __align__(16) char As[2][BM * BKB];   // 2 x 16 KiB
  __shared__ __align__(16) char Bs[2][BN * BKB];   // 2 x 16 KiB

  // XCD-aware bijective remap: each XCD owns 32 consecutive logical blocks
  const int id = (blockIdx.x & 7) * (GRID_BLOCKS / 8) + (blockIdx.x >> 3);
  const int z  = id >> 6;          // 64 blocks per z-plane
  const int p  = id & 63;
  const int by = p >> 2;           // 16 M-tiles
  const int bx = p & 3;            // 4 N-tiles
  const int bm0 = by * BM;
  const int bn0 = bx * BN;
  const int kt0 = z * KZ;

  const int tid  = threadIdx.x;
  const int wave = tid >> 6;
  const int lane = tid & 63;
  const int quad = lane >> 4;
  const int lm   = lane & 15;
  const int wm   = (wave >> 2) * 128;   // 2 M-wave-groups
  const int wn   = (wave & 3) * 64;     // 4 N-wave-groups

  // staging decode: lane -> slot (row = rb+(lane>>2), gs = lane&3);
  // global group gg = gs ^ ((row>>1)&3)
  const int r4 = lane >> 2;
  const int gg = (lane & 3) ^ ((lane >> 3) & 3);

  const char* pA0 = A + (size_t)(bm0 + wave * 32 + r4) * KDIM + kt0 + gg * 16;
  const char* pB0 = C + (size_t)(bn0 + wave * 32 + r4) * KDIM + kt0 + gg * 16;
  const int lo = wave * 32 * BKB;   // wave's LDS base within a slot

  const int kx   = (quad ^ ((lm >> 1) & 3)) * 16;   // swizzled ds_read group offset
  const int aoff = (wm + lm) * BKB + kx;            // + f*FRAG per fragment
  const int boff = (wn + lm) * BKB + kx;

  v4i acc[8][4] = {};
  v4u g0A0, g0A1, g0B0, g0B1;   // reg set 0 (even data)
  v4u g1A0, g1A1, g1B0, g1B1;   // reg set 1 (odd data)

#define GLOAD(A0, A1, B0, B1)                                                \
  {                                                                          \
    A0 = *(const v4u*)(pA0);                                                 \
    A1 = *(const v4u*)(pA0 + (size_t)16 * KDIM);                             \
    B0 = *(const v4u*)(pB0);                                                 \
    B1 = *(const v4u*)(pB0 + (size_t)16 * KDIM);                             \
    pA0 += BKB; pB0 += BKB;                                                  \
  }

#define DSWRITE(SL, A0, A1, B0, B1)                                          \
  {                                                                          \
    *(v4u*)(As[SL] + lo + lane * 16)            = A0;                        \
    *(v4u*)(As[SL] + lo + 16 * BKB + lane * 16) = A1;                        \
    *(v4u*)(Bs[SL] + lo + lane * 16)            = B0;                        \
    *(v4u*)(Bs[SL] + lo + 16 * BKB + lane * 16) = B1;                        \
  }

  // STEP(t): cur = t&1. Load data t+2 (top), read slot[cur], write data t+1
  // (compiler emits the counted vmcnt for its registers), MFMA, __syncthreads.
#define GSTEP(CUR, LA0, LA1, LB0, LB1, WA0, WA1, WB0, WB1, DOGLOAD, DOWRITE, DOBAR) \
  {                                                                          \
    if (DOGLOAD) GLOAD(LA0, LA1, LB0, LB1)                                   \
    const char* cA = As[CUR] + aoff;                                         \
    const char* cB = Bs[CUR] + boff;                                         \
    v4i a[8], b[4];                                                          \
    _Pragma("unroll")                                                        \
    for (int f = 0; f < 4; ++f) a[f] = *(const v4i*)(cA + f * FRAG);         \
    _Pragma("unroll")                                                        \
    for (int f = 0; f < 4; ++f) b[f] = *(const v4i*)(cB + f * FRAG);         \
    _Pragma("unroll")                                                        \
    for (int f = 4; f < 8; ++f) a[f] = *(const v4i*)(cA + f * FRAG);         \
    if (DOWRITE) DSWRITE(CUR ^ 1, WA0, WA1, WB0, WB1)                        \
    __builtin_amdgcn_s_setprio(1);                                           \
    _Pragma("unroll")                                                        \
    for (int fm = 0; fm < 4; ++fm)                                           \
      _Pragma("unroll")                                                      \
      for (int fn = 0; fn < 4; ++fn)                                         \
        acc[fm][fn] = __builtin_amdgcn_mfma_i32_16x16x64_i8(a[fm], b[fn], acc[fm][fn], 0, 0, 0); \
    _Pragma("unroll")                                                        \
    for (int fm = 4; fm < 8; ++fm)                                           \
      _Pragma("unroll")                                                      \
      for (int fn = 0; fn < 4; ++fn)                                         \
        acc[fm][fn] = __builtin_amdgcn_mfma_i32_16x16x64_i8(a[fm], b[fn], acc[fm][fn], 0, 0, 0); \
    __builtin_amdgcn_s_setprio(0);                                           \
    if (DOBAR) __syncthreads();                                              \
  }

  // prologue: data0 -> set0 -> slot0; data1 -> set1 (stays in regs)
  GLOAD(g0A0, g0A1, g0B0, g0B1)                       // data 0
  GLOAD(g1A0, g1A1, g1B0, g1B1)                       // data 1
  DSWRITE(0, g0A0, g0A1, g0B0, g0B1)                  // compiler waits on data 0
  __syncthreads();                                    // slot0 published

  // t = 0..29: 15 pairs; even t loads -> set0, writes set1 (data t+1); odd mirrored
  for (int i = 0; i < 15; ++i) {
    GSTEP(0, g0A0, g0A1, g0B0, g0B1, g1A0, g1A1, g1B0, g1B1, true, true, true)
    GSTEP(1, g1A0, g1A1, g1B0, g1B1, g0A0, g0A1, g0B0, g0B1, true, true, true)
  }
  // t = 30: no load; write set1 (data 31, loaded at t=29) -> slot1
  GSTEP(0, g0A0, g0A1, g0B0, g0B1, g1A0, g1A1, g1B0, g1B1, false, true, true)
  // t = 31: no load, no write, no closing barrier
  GSTEP(1, g1A0, g1A1, g1B0, g1B1, g0A0, g0A1, g0B0, g0B1, false, false, false)
#undef GSTEP
#undef DSWRITE
#undef GLOAD

  // ---- packed epilogue: 64 bf16-pair words per lane, 16 coalesced dwordx4 stores ----
  unsigned w32[64];
#pragma unroll
  for (int fm = 0; fm < 8; ++fm)
#pragma unroll
    for (int fn = 0; fn < 4; ++fn)
#pragma unroll
      for (int rr = 0; rr < 2; ++rr)
        w32[fm * 8 + fn * 2 + rr] =
            (unsigned)f2bf((float)acc[fm][fn][2 * rr]) |
            ((unsigned)f2bf((float)acc[fm][fn][2 * rr + 1]) << 16);

  unsigned* outp = partials + (((size_t)z * 64 + p) * 8 + wave) * 4096 + lane * 4;
#pragma unroll
  for (int c = 0; c < 16; ++c)
    *(v4u*)(outp + c * 256) = v4u{w32[4 * c], w32[4 * c + 1], w32[4 * c + 2], w32[4 * c + 3]};
}

// ---------------- Phase 3: reduce + dequant + un-pack transpose ----------------
// One block per (p, w) 128x64 output region; sums 4 z-copies of the packed
// region (fully coalesced dwordx4), decodes (chunk,lane,word)->(b,o), dequants,
// transposes through LDS, writes out [b][o] coalesced. (Verified R8.)
__global__ __launch_bounds__(256) void reduce_kernel(
    const unsigned* __restrict__ P, const float* __restrict__ maxrow,
    const int* __restrict__ qcsum, float* __restrict__ out) {
  const int blk = blockIdx.x;         // 0..511
  const int p = blk >> 3, w = blk & 7;
  const int by = p >> 2, bx = p & 3;
  const int B0 = by * BM + (w >> 2) * 128;
  const int O0 = bx * BN + (w & 3) * 64;
  const int t = threadIdx.x;
  const int l = t & 63;

  __shared__ float tile[128][65];
  __shared__ float sM[64];
  __shared__ float sQ[64];
  if (t < 64) { sM[t] = maxrow[O0 + t]; sQ[t] = 127.0f * (float)qcsum[O0 + t]; }
  __syncthreads();

  const size_t region = ((size_t)p * 8 + w) * 4096;
  const size_t zs     = (size_t)64 * 8 * 4096;   // u32 per z-plane
  float slo[16] = {}, shi[16] = {};
#pragma unroll
  for (int z = 0; z < SPLITS; ++z) {
#pragma unroll
    for (int r = 0; r < 4; ++r) {
      v4u u = *(const v4u*)(P + z * zs + region + ((t >> 6) + r * 4) * 256 + l * 4);
#pragma unroll
      for (int i = 0; i < 4; ++i) {
        slo[r * 4 + i] += bf2f((unsigned short)(u[i] & 0xFFFFu));
        shi[r * 4 + i] += bf2f((unsigned short)(u[i] >> 16));
      }
    }
  }
  const float inv = 1.0f / 32258.0f;   // 127*254
#pragma unroll
  for (int r = 0; r < 4; ++r)
#pragma unroll
    for (int i = 0; i < 4; ++i) {
      const int jj = (t >> 6) * 4 + r * 16 + i;       // fm*8 + fn*2 + rr
      const int fm = jj >> 3, fn = (jj >> 1) & 3, rr = jj & 1;
      const int bl = fm * 16 + (l >> 4) * 4 + rr * 2;
      const int ol = fn * 16 + (l & 15);
      const float M = sM[ol], corr = sQ[ol];
      tile[bl][ol]     = M * (slo[r * 4 + i] + corr) * inv;
      tile[bl + 1][ol] = M * (shi[r * 4 + i] + corr) * inv;
    }
  __syncthreads();

  const int row = t >> 1;
  const int c0  = (t & 1) * 32;
  float* op = out + (size_t)(B0 + row) * OUTC + O0 + c0;
#pragma unroll
  for (int i = 0; i < 8; ++i)
    *(float4*)(op + 4 * i) = float4{tile[row][c0 + 4 * i],     tile[row][c0 + 4 * i + 1],
                                    tile[row][c0 + 4 * i + 2], tile[row][c0 + 4 * i + 3]};
}

extern "C" void kernel_launch(void* const* d_in, const int* in_sizes, int n_in,
                              void* d_out, int out_size, void* d_ws, size_t ws_size,
                              hipStream_t stream) {
  const float* x       = (const float*)d_in[0];
  const float* coeffs  = (const float*)d_in[1];
  const float* centers = (const float*)d_in[2];
  const float* slopes  = (const float*)d_in[3];
  const float* alpha   = (const float*)d_in[4];
  const float* beta    = (const float*)d_in[5];
  float* out = (float*)d_out;

  const size_t a_bytes    = (size_t)BATCH * KDIM;                 // 32 MiB i8
  const size_t c_bytes    = (size_t)OUTC * KDIM;                  // 8 MiB i8
  const size_t stat_bytes = OUTC * sizeof(float);                 // 4 KiB
  const size_t qcs_bytes  = OUTC * sizeof(int);                   // 4 KiB
  const size_t part_bytes = (size_t)SPLITS * BATCH * OUTC * 2;    // 32 MiB bf16-pairs
  if (ws_size < a_bytes + c_bytes + stat_bytes + qcs_bytes + part_bytes) return;

  char*  Ai8    = (char*)d_ws;
  char*  Ci8    = Ai8 + a_bytes;
  float* maxrow = (float*)(Ci8 + c_bytes);
  int*   qcsum  = (int*)((char*)maxrow + stat_bytes);
  unsigned* parts = (unsigned*)((char*)qcsum + qcs_bytes);

  prep_kernel<<<PREP_BLOCKS, 256, 0, stream>>>(
      x, (const float4*)coeffs, centers, slopes, alpha, beta,
      Ai8, (int*)Ci8, maxrow, qcsum);

  gemm_kernel<<<GRID_BLOCKS, 512, 0, stream>>>(Ai8, Ci8, parts);

  reduce_kernel<<<64 * 8, 256, 0, stream>>>(parts, maxrow, qcsum, out);
}